// Round 1
// baseline (2462.434 us; speedup 1.0000x reference)
//
#include <hip/hip_runtime.h>
#include <hip/hip_bf16.h>

typedef unsigned short u16;
typedef __attribute__((ext_vector_type(8))) short bf16x8;
typedef __attribute__((ext_vector_type(4))) float f32x4;
typedef __attribute__((ext_vector_type(8))) unsigned short u16x8;

#define MFMA16 __builtin_amdgcn_mfma_f32_16x16x32_bf16

__device__ inline u16 f2bf(float f) {
    union { float f; unsigned u; } v; v.f = f;
    unsigned u = v.u;
    u += 0x7fffu + ((u >> 16) & 1u);   // round-to-nearest-even
    return (u16)(u >> 16);
}

// ---------------- cast fp32 -> bf16, 8 elems/thread ----------------
__global__ __launch_bounds__(256) void cast_kernel(const float* __restrict__ in,
                                                   u16* __restrict__ out, int n8) {
    int i = blockIdx.x * 256 + threadIdx.x;
    if (i >= n8) return;
    const float4* p4 = (const float4*)in;
    float4 a = p4[2 * (size_t)i], b = p4[2 * (size_t)i + 1];
    u16x8 o;
    o[0] = f2bf(a.x); o[1] = f2bf(a.y); o[2] = f2bf(a.z); o[3] = f2bf(a.w);
    o[4] = f2bf(b.x); o[5] = f2bf(b.y); o[6] = f2bf(b.z); o[7] = f2bf(b.w);
    *(u16x8*)(out + 8 * (size_t)i) = o;
}

// ---------------- bf16 MFMA GEMM: C[M,N] = A[M,K] * B[K,N] ----------------
// 128x128 tile, BK=32, 256 threads (4 waves, each 64x64 = 4x4 MFMA tiles)
template <int OUT_BF16>
__global__ __launch_bounds__(256) void gemm_kernel(const u16* __restrict__ A,
                                                   const u16* __restrict__ B,
                                                   void* __restrict__ Cv,
                                                   int M, int N, int K) {
    __shared__ __align__(16) u16 As[128 * 40];   // stride 40 bf16 (80B): 2-way-free banks
    __shared__ __align__(16) u16 Bt[128 * 40];   // B transposed: Bt[n][k]

    const int tid  = threadIdx.x;
    const int lane = tid & 63;
    const int wave = tid >> 6;
    const int l16  = lane & 15;
    const int quad = lane >> 4;
    const int wm   = (wave >> 1) * 64;
    const int wn   = (wave & 1) * 64;
    const int m0   = blockIdx.x * 128;
    const int n0   = blockIdx.y * 128;

    f32x4 acc[4][4];
#pragma unroll
    for (int i = 0; i < 4; i++)
#pragma unroll
        for (int j = 0; j < 4; j++) acc[i][j] = (f32x4){0.f, 0.f, 0.f, 0.f};

    for (int kk = 0; kk < K; kk += 32) {
        // stage A tile [128][32]
#pragma unroll
        for (int p = 0; p < 2; p++) {
            int idx = p * 256 + tid;
            int r = idx >> 2;
            int c = (idx & 3) * 8;
            int gm = m0 + r;
            u16x8 v = {0, 0, 0, 0, 0, 0, 0, 0};
            if (gm < M) v = *(const u16x8*)(A + (size_t)gm * K + kk + c);
            *(u16x8*)(&As[r * 40 + c]) = v;
        }
        // stage B tile [32][128] transposed -> Bt[n][k]
#pragma unroll
        for (int p = 0; p < 2; p++) {
            int idx = p * 256 + tid;
            int k = idx >> 4;
            int c = (idx & 15) * 8;
            u16x8 v = *(const u16x8*)(B + (size_t)(kk + k) * N + n0 + c);
#pragma unroll
            for (int ii = 0; ii < 8; ii++) Bt[(c + ii) * 40 + k] = v[ii];
        }
        __syncthreads();

        bf16x8 af[4], bfr[4];
#pragma unroll
        for (int mt = 0; mt < 4; mt++)
            af[mt] = *(const bf16x8*)(&As[(wm + mt * 16 + l16) * 40 + quad * 8]);
#pragma unroll
        for (int nt = 0; nt < 4; nt++)
            bfr[nt] = *(const bf16x8*)(&Bt[(wn + nt * 16 + l16) * 40 + quad * 8]);
#pragma unroll
        for (int mt = 0; mt < 4; mt++)
#pragma unroll
            for (int nt = 0; nt < 4; nt++)
                acc[mt][nt] = MFMA16(af[mt], bfr[nt], acc[mt][nt], 0, 0, 0);
        __syncthreads();
    }

    // epilogue: C row = quad*4+r, col = l16 (verified layout)
#pragma unroll
    for (int mt = 0; mt < 4; mt++) {
#pragma unroll
        for (int nt = 0; nt < 4; nt++) {
#pragma unroll
            for (int r = 0; r < 4; r++) {
                int gm = m0 + wm + mt * 16 + quad * 4 + r;
                int gn = n0 + wn + nt * 16 + l16;
                if (gm < M) {
                    if (OUT_BF16)
                        ((u16*)Cv)[(size_t)gm * N + gn] = f2bf(acc[mt][nt][r]);
                    else
                        ((float*)Cv)[(size_t)gm * N + gn] = acc[mt][nt][r];
                }
            }
        }
    }
}

// ---------------- fused window attention: 1 wave per (b,w,h) ----------------
// qkv: [153664 tokens][1536], col = s*512 + h*32 + d
__global__ __launch_bounds__(64) void attn_kernel(const u16* __restrict__ qkv,
                                                  const float* __restrict__ bias_table,
                                                  u16* __restrict__ aout) {
    __shared__ __align__(16) float Sm[64 * 65];   // scores, stride 65 (odd: 2-way-free)
    __shared__ __align__(16) u16 Pm[64 * 88];     // probs bf16, stride 88 (16B-aligned rows)

    const int lane = threadIdx.x;
    const int l16  = lane & 15;
    const int quad = lane >> 4;
    const int bwh  = blockIdx.x;
    const int h    = bwh & 15;
    const int bw   = bwh >> 4;
    const size_t base = (size_t)bw * 49;

    const bf16x8 z8 = {0, 0, 0, 0, 0, 0, 0, 0};

    // Q/K fragments: A-layout lane holds [m=l16][k=quad*8+j] (k = d, K=32 = full head dim)
    bf16x8 qf[4], kf[4];
#pragma unroll
    for (int t = 0; t < 4; t++) {
        int m = t * 16 + l16;
        qf[t] = (m < 49) ? *(const bf16x8*)(qkv + (base + m) * 1536 + h * 32 + quad * 8) : z8;
        kf[t] = (m < 49) ? *(const bf16x8*)(qkv + (base + m) * 1536 + 512 + h * 32 + quad * 8) : z8;
    }

    // S = Q K^T * scale + bias  (store to LDS; only cols j<49 ever read)
    const f32x4 zf = {0.f, 0.f, 0.f, 0.f};
#pragma unroll
    for (int mt = 0; mt < 4; mt++) {
#pragma unroll
        for (int nt = 0; nt < 4; nt++) {
            f32x4 s = MFMA16(qf[mt], kf[nt], zf, 0, 0, 0);
            int j = nt * 16 + l16;
            if (j < 49) {
                int rj = j / 7, cj = j - rj * 7;
#pragma unroll
                for (int r = 0; r < 4; r++) {
                    int i = mt * 16 + quad * 4 + r;
                    float val = s[r] * 0.17677669529663687f;
                    if (i < 49) {
                        int ri = i / 7, ci = i - ri * 7;
                        int idx = (ri - rj + 6) * 13 + (ci - cj + 6);
                        val += bias_table[idx * 16 + h];
                    }
                    Sm[i * 65 + j] = val;
                }
            }
        }
    }
    __syncthreads();

    // softmax: one row per lane (rows >=49 are harmless finite garbage, never stored)
    {
        int r = lane;
        float mx = -1e30f;
        for (int j = 0; j < 49; j++) mx = fmaxf(mx, Sm[r * 65 + j]);
        float sum = 0.f;
        for (int j = 0; j < 49; j++) {
            float e = __expf(Sm[r * 65 + j] - mx);
            Sm[r * 65 + j] = e;
            sum += e;
        }
        float inv = 1.f / sum;
        for (int j = 0; j < 49; j++) Pm[r * 88 + j] = f2bf(Sm[r * 65 + j] * inv);
        for (int j = 49; j < 64; j++) Pm[r * 88 + j] = 0;  // zero pad (k-dim of PV)
    }
    __syncthreads();

    // V fragments: B-layout lane holds V[k=ks*32+quad*8+jj][n=nt*16+l16]
    bf16x8 vf[2][2];
#pragma unroll
    for (int ks = 0; ks < 2; ks++) {
#pragma unroll
        for (int nt = 0; nt < 2; nt++) {
            u16x8 tmp;
#pragma unroll
            for (int jj = 0; jj < 8; jj++) {
                int tok = ks * 32 + quad * 8 + jj;
                tmp[jj] = (tok < 49)
                              ? qkv[(base + tok) * 1536 + 1024 + h * 32 + nt * 16 + l16]
                              : (u16)0;
            }
            vf[ks][nt] = *(bf16x8*)&tmp;
        }
    }

    f32x4 o[4][2];
#pragma unroll
    for (int mt = 0; mt < 4; mt++) { o[mt][0] = zf; o[mt][1] = zf; }
#pragma unroll
    for (int mt = 0; mt < 4; mt++) {
#pragma unroll
        for (int ks = 0; ks < 2; ks++) {
            bf16x8 p = *(const bf16x8*)(&Pm[(mt * 16 + l16) * 88 + ks * 32 + quad * 8]);
            o[mt][0] = MFMA16(p, vf[ks][0], o[mt][0], 0, 0, 0);
            o[mt][1] = MFMA16(p, vf[ks][1], o[mt][1], 0, 0, 0);
        }
    }

    // store attention out as bf16: [token][h*32+d]
#pragma unroll
    for (int mt = 0; mt < 4; mt++) {
#pragma unroll
        for (int r = 0; r < 4; r++) {
            int i = mt * 16 + quad * 4 + r;
            if (i < 49) {
#pragma unroll
                for (int nt = 0; nt < 2; nt++)
                    aout[(base + i) * 512 + h * 32 + nt * 16 + l16] = f2bf(o[mt][nt][r]);
            }
        }
    }
}

extern "C" void kernel_launch(void* const* d_in, const int* in_sizes, int n_in,
                              void* d_out, int out_size, void* d_ws, size_t ws_size,
                              hipStream_t stream) {
    const float* x          = (const float*)d_in[0];  // [16,196,49,512]
    const float* w_qkv      = (const float*)d_in[1];  // [512,1536]
    const float* bias_table = (const float*)d_in[2];  // [169,16]
    const float* w_out      = (const float*)d_in[3];  // [512,512]
    float* out = (float*)d_out;

    // workspace layout (602 MB): xb | qkvb | wqkvb | woutb ; attn-out reuses xb
    char* ws = (char*)d_ws;
    u16* xb    = (u16*)ws;                                           // 157,351,936 B
    u16* qkvb  = (u16*)(ws + 157351936LL);                           // 472,055,808 B
    u16* wqkvb = (u16*)(ws + 157351936LL + 472055808LL);             // 1,572,864 B
    u16* woutb = (u16*)(ws + 157351936LL + 472055808LL + 1572864LL); // 524,288 B
    u16* aob   = xb;  // xb dead after GEMM1

    cast_kernel<<<38416, 256, 0, stream>>>(x, xb, 9834496);
    cast_kernel<<<384, 256, 0, stream>>>(w_qkv, wqkvb, 98304);
    cast_kernel<<<128, 256, 0, stream>>>(w_out, woutb, 32768);

    // qkv = x @ w_qkv   [153664,512]x[512,1536] -> bf16
    gemm_kernel<1><<<dim3(1201, 12), 256, 0, stream>>>(xb, wqkvb, qkvb, 153664, 1536, 512);

    // windowed attention, 1 wave per (b,w,h)
    attn_kernel<<<50176, 64, 0, stream>>>(qkvb, bias_table, aob);

    // out = attn_out @ w_out   [153664,512]x[512,512] -> fp32
    gemm_kernel<0><<<dim3(1201, 4), 256, 0, stream>>>(aob, woutb, out, 153664, 512, 512);
}

// Round 2
// 1296.870 us; speedup vs baseline: 1.8988x; 1.8988x over previous
//
#include <hip/hip_runtime.h>
#include <hip/hip_bf16.h>

typedef unsigned short u16;
typedef __attribute__((ext_vector_type(8))) short bf16x8;
typedef __attribute__((ext_vector_type(4))) float f32x4;
typedef __attribute__((ext_vector_type(8))) unsigned short u16x8;

#define MFMA16 __builtin_amdgcn_mfma_f32_16x16x32_bf16

__device__ inline u16 f2bf(float f) {
    union { float f; unsigned u; } v; v.f = f;
    unsigned u = v.u;
    u += 0x7fffu + ((u >> 16) & 1u);   // round-to-nearest-even
    return (u16)(u >> 16);
}

// async global -> LDS, 16B per lane (global_load_lds_dwordx4)
__device__ __forceinline__ void gl_lds16(const u16* g, u16* l) {
    __builtin_amdgcn_global_load_lds(
        (const __attribute__((address_space(1))) unsigned int*)g,
        (__attribute__((address_space(3))) unsigned int*)l, 16, 0, 0);
}

// ---------------- cast fp32 -> bf16, 8 elems/thread ----------------
__global__ __launch_bounds__(256) void cast_kernel(const float* __restrict__ in,
                                                   u16* __restrict__ out, int n8) {
    int i = blockIdx.x * 256 + threadIdx.x;
    if (i >= n8) return;
    const float4* p4 = (const float4*)in;
    float4 a = p4[2 * (size_t)i], b = p4[2 * (size_t)i + 1];
    u16x8 o;
    o[0] = f2bf(a.x); o[1] = f2bf(a.y); o[2] = f2bf(a.z); o[3] = f2bf(a.w);
    o[4] = f2bf(b.x); o[5] = f2bf(b.y); o[6] = f2bf(b.z); o[7] = f2bf(b.w);
    *(u16x8*)(out + 8 * (size_t)i) = o;
}

// -------- cast+transpose weights: in[K=512][N] fp32 -> out[N][512] bf16 ------
__global__ __launch_bounds__(256) void castT_kernel(const float* __restrict__ in,
                                                    u16* __restrict__ out, int N, int total) {
    int i = blockIdx.x * 256 + threadIdx.x;  // i = n*512 + k
    if (i >= total) return;
    int n = i >> 9, k = i & 511;
    out[i] = f2bf(in[(size_t)k * N + n]);    // tiny (3MB), L2-resident
}

// ---------------- bf16 MFMA GEMM (m97 recipe): C[M,N] = A[M,K] * Bt[N,K]^T ---
// 128x128 tile, BK=32, 256 threads (4 waves of 64x64), global_load_lds staging.
// blockIdx.x = n-tile (fastest -> consecutive blocks share the A tile).
template <int OUT_BF16>
__global__ __launch_bounds__(256) void gemm_bt_kernel(const u16* __restrict__ A,
                                                      const u16* __restrict__ Bt,
                                                      void* __restrict__ Cv,
                                                      int M, int N, int K) {
    __shared__ __align__(16) u16 As[128 * 32];  // unpadded: global_load_lds layout
    __shared__ __align__(16) u16 Bs[128 * 32];

    const int tid  = threadIdx.x;
    const int lane = tid & 63;
    const int wave = tid >> 6;
    const int l16  = lane & 15;
    const int quad = lane >> 4;
    const int wm   = (wave >> 1) * 64;
    const int wn   = (wave & 1) * 64;
    const int n0   = blockIdx.x * 128;
    const int m0   = blockIdx.y * 128;
    const bool full = (m0 + 128 <= M);

    f32x4 acc[4][4];
#pragma unroll
    for (int i = 0; i < 4; i++)
#pragma unroll
        for (int j = 0; j < 4; j++) acc[i][j] = (f32x4){0.f, 0.f, 0.f, 0.f};

    for (int kk = 0; kk < K; kk += 32) {
        if (full) {
#pragma unroll
            for (int p = 0; p < 2; p++) {
                int idx = tid + p * 256;           // uniform-base + lane form
                int r = idx >> 2, c = (idx & 3) << 3;
                gl_lds16(A + (size_t)(m0 + r) * K + kk + c, As + idx * 8);
                gl_lds16(Bt + (size_t)(n0 + r) * K + kk + c, Bs + idx * 8);
            }
        } else {  // ragged M tail (1 of 1201 block-rows): guarded VGPR path for A
#pragma unroll
            for (int p = 0; p < 2; p++) {
                int idx = tid + p * 256;
                int r = idx >> 2, c = (idx & 3) << 3;
                u16x8 v = {0, 0, 0, 0, 0, 0, 0, 0};
                if (m0 + r < M) v = *(const u16x8*)(A + (size_t)(m0 + r) * K + kk + c);
                *(u16x8*)(As + idx * 8) = v;
                gl_lds16(Bt + (size_t)(n0 + r) * K + kk + c, Bs + idx * 8);
            }
        }
        __syncthreads();

        bf16x8 af[4], bfr[4];
#pragma unroll
        for (int mt = 0; mt < 4; mt++)
            af[mt] = *(const bf16x8*)(&As[(wm + mt * 16 + l16) * 32 + quad * 8]);
#pragma unroll
        for (int nt = 0; nt < 4; nt++)
            bfr[nt] = *(const bf16x8*)(&Bs[(wn + nt * 16 + l16) * 32 + quad * 8]);
#pragma unroll
        for (int mt = 0; mt < 4; mt++)
#pragma unroll
            for (int nt = 0; nt < 4; nt++)
                acc[mt][nt] = MFMA16(af[mt], bfr[nt], acc[mt][nt], 0, 0, 0);
        __syncthreads();
    }

    // epilogue: C row = quad*4+r, col = l16 (verified layout)
#pragma unroll
    for (int mt = 0; mt < 4; mt++) {
#pragma unroll
        for (int nt = 0; nt < 4; nt++) {
#pragma unroll
            for (int r = 0; r < 4; r++) {
                int gm = m0 + wm + mt * 16 + quad * 4 + r;
                int gn = n0 + wn + nt * 16 + l16;
                if (gm < M) {
                    if (OUT_BF16)
                        ((u16*)Cv)[(size_t)gm * N + gn] = f2bf(acc[mt][nt][r]);
                    else
                        ((float*)Cv)[(size_t)gm * N + gn] = acc[mt][nt][r];
                }
            }
        }
    }
}

// ---------------- fused window attention: 1 wave per (b,w,h) ----------------
// Register softmax (shuffle-reduce), LDS only for P round-trip + V^T + bias.
// LDS = 14.5KB/wave -> ~11 waves/CU (was 28KB -> 5).
__global__ __launch_bounds__(64) void attn_kernel(const u16* __restrict__ qkv,
                                                  const float* __restrict__ bias_table,
                                                  u16* __restrict__ aout) {
    __shared__ __align__(16) u16 Pm[64 * 72];    // probs bf16, stride 72 (144B, 16B-aligned)
    __shared__ __align__(16) u16 VmT[32 * 72];   // V^T: [d][tok]
    __shared__ float Bi[176];                    // bias row for this head

    const int lane = threadIdx.x;
    const int l16  = lane & 15;
    const int quad = lane >> 4;
    const int h    = blockIdx.x & 15;
    const int bw   = blockIdx.x >> 4;
    const size_t qb = (size_t)bw * 49 * 1536 + h * 32;
    const size_t ob = (size_t)bw * 49 * 512 + h * 32;

    // stage per-head bias into LDS
    for (int t = lane; t < 169; t += 64) Bi[t] = bias_table[t * 16 + h];
    // zero V^T pad columns (tok 48..63); real tok=48 is overwritten below (same-wave order)
    for (int t = lane; t < 32 * 16; t += 64) {
        int d = t >> 4, tok = 48 + (t & 15);
        VmT[d * 72 + tok] = 0;
    }

    const bf16x8 z8 = {0, 0, 0, 0, 0, 0, 0, 0};
    const f32x4 zf = {0.f, 0.f, 0.f, 0.f};

    // Q/K A-frags: lane holds [m=l16][k=quad*8+j], k = head dim (K=32 full)
    bf16x8 qf[4], kf[4];
#pragma unroll
    for (int t = 0; t < 4; t++) {
        int m = t * 16 + l16;
        bool v = m < 49;
        qf[t] = v ? *(const bf16x8*)(qkv + qb + (size_t)m * 1536 + quad * 8) : z8;
        kf[t] = v ? *(const bf16x8*)(qkv + qb + 512 + (size_t)m * 1536 + quad * 8) : z8;
        if (v) {  // stage V row -> V^T in LDS (coalesced global read, scalar LDS writes)
            u16x8 v8 = *(const u16x8*)(qkv + qb + 1024 + (size_t)m * 1536 + quad * 8);
#pragma unroll
            for (int jj = 0; jj < 8; jj++) VmT[(quad * 8 + jj) * 72 + m] = v8[jj];
        }
    }

    // S = Q K^T (C-layout: row = quad*4+r, col = nt*16+l16)
    f32x4 s[4][4];
#pragma unroll
    for (int mt = 0; mt < 4; mt++)
#pragma unroll
        for (int nt = 0; nt < 4; nt++) s[mt][nt] = MFMA16(qf[mt], kf[nt], zf, 0, 0, 0);

    // scale + bias + column mask, in registers
#pragma unroll
    for (int nt = 0; nt < 4; nt++) {
        int j = nt * 16 + l16;
        int rj = j / 7, cj = j - rj * 7;
#pragma unroll
        for (int mt = 0; mt < 4; mt++) {
#pragma unroll
            for (int r = 0; r < 4; r++) {
                int i = mt * 16 + quad * 4 + r;
                if (j >= 49) {
                    s[mt][nt][r] = -1e30f;
                } else {
                    float val = s[mt][nt][r] * 0.17677669529663687f;
                    if (i < 49) {
                        int ri = i / 7, ci = i - ri * 7;
                        val += Bi[(ri - rj + 6) * 13 + (ci - cj + 6)];
                    }
                    s[mt][nt][r] = val;
                }
            }
        }
    }

    // register softmax: row max/sum via shuffle over the 16-lane l16 group
    float rsum[4][4];
#pragma unroll
    for (int mt = 0; mt < 4; mt++) {
#pragma unroll
        for (int r = 0; r < 4; r++) {
            float mx = fmaxf(fmaxf(s[mt][0][r], s[mt][1][r]), fmaxf(s[mt][2][r], s[mt][3][r]));
#pragma unroll
            for (int d = 1; d < 16; d <<= 1) mx = fmaxf(mx, __shfl_xor(mx, d, 64));
            float sum = 0.f;
#pragma unroll
            for (int nt = 0; nt < 4; nt++) {
                float e = __expf(s[mt][nt][r] - mx);
                s[mt][nt][r] = e;   // unnormalized P (norm deferred to O epilogue)
                sum += e;
            }
#pragma unroll
            for (int d = 1; d < 16; d <<= 1) sum += __shfl_xor(sum, d, 64);
            rsum[mt][r] = sum;
            // write P (bf16) to LDS in C-layout position
            int row = mt * 16 + quad * 4 + r;
#pragma unroll
            for (int nt = 0; nt < 4; nt++)
                Pm[row * 72 + nt * 16 + l16] = f2bf(s[mt][nt][r]);
        }
    }
    __syncthreads();  // single wave: compiles to waitcnt (cheap), orders LDS

    // V B-frags from V^T: lane holds V[k=ks*32+quad*8+j][n=nt*16+l16], vector reads
    bf16x8 vf[2][2];
#pragma unroll
    for (int ks = 0; ks < 2; ks++)
#pragma unroll
        for (int nt = 0; nt < 2; nt++)
            vf[ks][nt] = *(const bf16x8*)(&VmT[(nt * 16 + l16) * 72 + ks * 32 + quad * 8]);

    // O = P V
    f32x4 o[4][2];
#pragma unroll
    for (int mt = 0; mt < 4; mt++) { o[mt][0] = zf; o[mt][1] = zf; }
#pragma unroll
    for (int mt = 0; mt < 4; mt++) {
#pragma unroll
        for (int ks = 0; ks < 2; ks++) {
            bf16x8 p = *(const bf16x8*)(&Pm[(mt * 16 + l16) * 72 + ks * 32 + quad * 8]);
            o[mt][0] = MFMA16(p, vf[ks][0], o[mt][0], 0, 0, 0);
            o[mt][1] = MFMA16(p, vf[ks][1], o[mt][1], 0, 0, 0);
        }
    }

    // store with deferred softmax normalization
#pragma unroll
    for (int mt = 0; mt < 4; mt++) {
#pragma unroll
        for (int r = 0; r < 4; r++) {
            int i = mt * 16 + quad * 4 + r;
            if (i < 49) {
                float inv = 1.f / rsum[mt][r];
#pragma unroll
                for (int nt = 0; nt < 2; nt++)
                    aout[ob + (size_t)i * 512 + nt * 16 + l16] = f2bf(o[mt][nt][r] * inv);
            }
        }
    }
}

extern "C" void kernel_launch(void* const* d_in, const int* in_sizes, int n_in,
                              void* d_out, int out_size, void* d_ws, size_t ws_size,
                              hipStream_t stream) {
    const float* x          = (const float*)d_in[0];  // [16,196,49,512]
    const float* w_qkv      = (const float*)d_in[1];  // [512,1536]
    const float* bias_table = (const float*)d_in[2];  // [169,16]
    const float* w_out      = (const float*)d_in[3];  // [512,512]
    float* out = (float*)d_out;

    // workspace: xb | qkvb | wqkvT | woutT ; attn-out reuses xb
    char* ws = (char*)d_ws;
    u16* xb    = (u16*)ws;                                           // 157,351,936 B
    u16* qkvb  = (u16*)(ws + 157351936LL);                           // 472,055,808 B
    u16* wqkvT = (u16*)(ws + 157351936LL + 472055808LL);             // 1,572,864 B
    u16* woutT = (u16*)(ws + 157351936LL + 472055808LL + 1572864LL); // 524,288 B
    u16* aob   = xb;  // xb dead after GEMM1

    cast_kernel<<<38416, 256, 0, stream>>>(x, xb, 9834496);
    castT_kernel<<<3072, 256, 0, stream>>>(w_qkv, wqkvT, 1536, 786432);
    castT_kernel<<<1024, 256, 0, stream>>>(w_out, woutT, 512, 262144);

    // qkv = x @ w_qkv   [153664,512]x[512,1536] -> bf16 (grid: n fastest for A reuse)
    gemm_bt_kernel<1><<<dim3(12, 1201), 256, 0, stream>>>(xb, wqkvT, qkvb, 153664, 1536, 512);

    // windowed attention, 1 wave per (b,w,h)
    attn_kernel<<<50176, 64, 0, stream>>>(qkvb, bias_table, aob);

    // out = attn_out @ w_out   [153664,512]x[512,512] -> fp32
    gemm_bt_kernel<0><<<dim3(4, 1201), 256, 0, stream>>>(aob, woutT, out, 153664, 512, 512);
}